// Round 7
// baseline (302.193 us; speedup 1.0000x reference)
//
#include <hip/hip_runtime.h>
#include <float.h>
#include <math.h>

#define K_CODES 1024
#define DIM 64
#define T_LEN 8192
#define N_TOK 131072          // 16 * 8192 tokens
#define LO_SCALE 2048.0f
#define SLOP 24.0f            // covers fp32 MFMA-accum rounding (approx+exact chains), scaled units

typedef _Float16 half8 __attribute__((ext_vector_type(8)));  // 4 VGPRs: MFMA A/B frag
typedef float    f32x4 __attribute__((ext_vector_type(4)));  // MFMA C/D frag

#define MFMA16(a, b, c) __builtin_amdgcn_mfma_f32_16x16x32_f16((a), (b), (c), 0, 0, 0)

// ---------------- prep: codebook -> tiled f16 hi/lo + norms ----------------
// Tile ct (16 codes) = 4 KB: hi[q][code][j], lo(x2048) at +1024 (unchanged layout).
// New: per-code Sum(bh^2) and Sum(bl_s^2) for the rigorous prune margin.
__global__ void vq_prep(const float* __restrict__ cb,
                        _Float16* __restrict__ w,
                        float* __restrict__ wesq,
                        float* __restrict__ wbh2,
                        float* __restrict__ wbl2) {
    __shared__ float part_x[128], part_h[128], part_l[128];
    const int ct   = blockIdx.x;
    const int r    = threadIdx.x;
    const int halF = r >> 7;
    const int rr   = r & 127;
    const int q    = rr >> 4;
    const int code = rr & 15;

    const float* src = cb + (size_t)(ct * 16 + code) * DIM + q * 8;
    float4 v0 = *reinterpret_cast<const float4*>(src);
    float4 v1 = *reinterpret_cast<const float4*>(src + 4);
    float x[8] = {v0.x, v0.y, v0.z, v0.w, v1.x, v1.y, v1.z, v1.w};

    half8 o;
    float psx = 0.0f, psq = 0.0f;
    #pragma unroll
    for (int j = 0; j < 8; ++j) {
        _Float16 h = (_Float16)x[j];
        if (halF) {
            _Float16 lv = (_Float16)((x[j] - (float)h) * LO_SCALE);  // (x-h) exact in fp32
            o[j] = lv;
            psq = fmaf((float)lv, (float)lv, psq);    // Sum bl_s^2 (stored, scaled)
        } else {
            o[j] = h;
            psq = fmaf((float)h, (float)h, psq);      // Sum bh^2 (stored)
            psx = fmaf(x[j], x[j], psx);              // Sum e^2
        }
    }
    *reinterpret_cast<half8*>(w + (size_t)ct * 2048 + halF * 1024 + q * 128 + code * 8) = o;

    if (halF == 0) { part_x[rr] = psx; part_h[rr] = psq; }
    else           { part_l[rr] = psq; }
    __syncthreads();
    if (r < 16) {
        float sx = 0.0f, sh = 0.0f, sl = 0.0f;
        #pragma unroll
        for (int q2 = 0; q2 < 8; ++q2) {
            sx += part_x[q2 * 16 + r];
            sh += part_h[q2 * 16 + r];
            sl += part_l[q2 * 16 + r];
        }
        wesq[ct * 16 + r] = sx * LO_SCALE;   // 2048*||e||^2
        wbh2[ct * 16 + r] = sh;              // ||bh||^2
        wbl2[ct * 16 + r] = sl;              // ||bl_s||^2
    }
}

// ---------------- main: bound-and-prune ----------------
// r0-r6 lesson: the 3-pass exact structure is pinned at ~61us by MFMA(25us)+VALU(19us)+stalls;
// no schedule/occupancy change moves it. This round cuts WORK: phase 1 scores with hi*hi only
// (2 MFMAs/tile/chain, h-only loads), min2-argmin, and a rigorous certificate:
//   exact = approx + corr,  |corr| <= ||ah||*max||bl_s|| + ||al_s||*max||bh||  (Cauchy-Schwarz
//   on the actual stored f16 vectors) + SLOP for fp32-accum rounding.
// gap > 2*margin  =>  approx winner == exact (r0) winner == reference.
// Uncertified tokens (~1-2%) -> cooperative fp64 full rescan (cb streamed via LDS chunks).
__global__ __launch_bounds__(256, 2)
void vq_main(const float* __restrict__ in,
             const float* __restrict__ cb,
             const _Float16* __restrict__ w,
             const float* __restrict__ wesq,
             const float* __restrict__ wbh2,
             const float* __restrict__ wbl2,
             float* __restrict__ out) {
    __shared__ __align__(16) float esq4[K_CODES][4];  // 16 KB: {es,es,es,es} per code
    __shared__ int    idx_s[256];
    __shared__ int    queue[256];
    __shared__ int    qn;
    __shared__ float  wmx[8];
    __shared__ float  ebuf[64][65];                   // fallback code chunk (padded rows)
    __shared__ double fbest[256];
    __shared__ int    fidx[256];

    const int tid  = threadIdx.x;
    const int wave = tid >> 6;
    const int lane = tid & 63;
    const int lo4  = lane & 15;   // code residue (C col) / token residue (A m)
    const int quad = lane >> 4;   // k-octet selector; token-row group in C

    // ---- prologue: stage esq broadcast-x4, reduce max norms ----
    float pmh = 0.0f, pml = 0.0f;
    for (int k = tid; k < K_CODES; k += 256) {
        float e = wesq[k];
        float4 ev = {e, e, e, e};
        *reinterpret_cast<float4*>(&esq4[k][0]) = ev;
        pmh = fmaxf(pmh, wbh2[k]);
        pml = fmaxf(pml, wbl2[k]);
    }
    #pragma unroll
    for (int off = 1; off < 64; off <<= 1) {
        pmh = fmaxf(pmh, __shfl_xor(pmh, off, 64));
        pml = fmaxf(pml, __shfl_xor(pml, off, 64));
    }
    if (lane == 0) { wmx[wave] = pmh; wmx[4 + wave] = pml; }
    if (tid == 0) qn = 0;
    __syncthreads();
    const float BH = sqrtf(fmaxf(fmaxf(wmx[0], wmx[1]), fmaxf(wmx[2], wmx[3])));  // max||bh||
    const float BL = sqrtf(fmaxf(fmaxf(wmx[4], wmx[5]), fmaxf(wmx[6], wmx[7])));  // max||bl_s||

    const int strip = blockIdx.x * 256 + wave * 64;   // 64 tokens per wave
    const int b  = strip >> 13;
    const int t0 = strip & 8191;

    // ---- A: a_hs only (32 VGPR) + exact norm partials for the margin ----
    const float* xin = in + (size_t)b * DIM * T_LEN + t0;
    half8 a_hs[4][2];
    float marg[4];
    #pragma unroll
    for (int mt = 0; mt < 4; ++mt) {
        float nh = 0.0f, nl = 0.0f;
        #pragma unroll
        for (int s = 0; s < 2; ++s) {
            half8 hs;
            #pragma unroll
            for (int j = 0; j < 8; ++j) {
                const int d = s * 32 + quad * 8 + j;
                float xv = -2.0f * xin[(size_t)d * T_LEN + mt * 16 + lo4];
                _Float16 h = (_Float16)xv;
                float hf = (float)h;
                hs[j] = (_Float16)(hf * LO_SCALE);                  // exact exponent shift
                _Float16 lv = (_Float16)((xv - hf) * LO_SCALE);     // stored-lo equivalent
                float lf = (float)lv;
                nh = fmaf(hf, hf, nh);
                nl = fmaf(lf, lf, nl);
            }
            a_hs[mt][s] = hs;
        }
        // sum partials over the 4 quad-lanes of this token (lo4 fixed)
        nh += __shfl_xor(nh, 16, 64);  nh += __shfl_xor(nh, 32, 64);
        nl += __shfl_xor(nl, 16, 64);  nl += __shfl_xor(nl, 32, 64);
        marg[mt] = sqrtf(nh) * BL + sqrtf(nl) * BH + SLOP;   // token mt*16+lo4, scaled units
    }

    float b1[16], b2[16];
    int   i1[16];
    #pragma unroll
    for (int i = 0; i < 16; ++i) { b1[i] = FLT_MAX; b2[i] = FLT_MAX; i1[i] = 0; }

    const _Float16* wb = w + (size_t)lane * 8;

    // phase-1 step: es-init via one ds_read_b128, 2 MFMAs per chain, min2 argmin
    auto step = [&](const half8& h0, const half8& h1, int ct) {
        const int code = ct * 16 + lo4;
        f32x4 ci = *reinterpret_cast<const f32x4*>(&esq4[code][0]);
        f32x4 c0 = MFMA16(a_hs[0][0], h0, ci);
        f32x4 c1 = MFMA16(a_hs[1][0], h0, ci);
        f32x4 c2 = MFMA16(a_hs[2][0], h0, ci);
        f32x4 c3 = MFMA16(a_hs[3][0], h0, ci);
        c0 = MFMA16(a_hs[0][1], h1, c0);
        c1 = MFMA16(a_hs[1][1], h1, c1);
        c2 = MFMA16(a_hs[2][1], h1, c2);
        c3 = MFMA16(a_hs[3][1], h1, c3);
        f32x4 cc[4] = {c0, c1, c2, c3};
        #pragma unroll
        for (int mt = 0; mt < 4; ++mt) {
            #pragma unroll
            for (int r = 0; r < 4; ++r) {
                float sc = cc[mt][r];
                const int i = mt * 4 + r;
                bool lt = sc < b1[i];
                float mn2 = fminf(b2[i], sc);
                b2[i] = lt ? b1[i] : mn2;
                b1[i] = lt ? sc : b1[i];
                i1[i] = lt ? code : i1[i];
            }
        }
    };
    auto loadH = [&](int ct, half8& h0, half8& h1) {
        const _Float16* p = wb + (size_t)ct * 2048;
        h0 = *reinterpret_cast<const half8*>(p);         // hi, k 0..31
        h1 = *reinterpret_cast<const half8*>(p + 512);   // hi, k 32..63
    };

    half8 A0, A1, B0, B1;
    loadH(0, A0, A1);
    loadH(1, B0, B1);
    for (int p = 0; p < 31; ++p) {
        step(A0, A1, 2 * p);     loadH(2 * p + 2, A0, A1);
        step(B0, B1, 2 * p + 1); loadH(2 * p + 3, B0, B1);
    }
    step(A0, A1, 62);
    step(B0, B1, 63);

    // ---- cross-lane min2 merge + certificate ----
    #pragma unroll
    for (int i = 0; i < 16; ++i) {
        float s = b1[i], s2 = b2[i];
        int ix = i1[i];
        #pragma unroll
        for (int off = 1; off < 16; off <<= 1) {
            float os  = __shfl_xor(s,  off, 64);
            float os2 = __shfl_xor(s2, off, 64);
            int  oix  = __shfl_xor(ix, off, 64);
            float mx = fmaxf(s, os);
            s2 = fminf(fminf(s2, os2), mx);          // union 2nd-smallest
            bool take = (os < s) || (os == s && oix < ix);
            s  = take ? os  : s;
            ix = take ? oix : ix;
        }
        float mtok = __shfl(marg[i >> 2], quad * 16 + quad * 4 + (i & 3), 64);
        if (lo4 == 0) {
            int tl = wave * 64 + (i >> 2) * 16 + quad * 4 + (i & 3);
            idx_s[tl] = ix;
            if (!(s2 - s > 2.0f * mtok)) {           // not certified -> exact rescan
                int slot = atomicAdd(&qn, 1);
                queue[slot] = tl;
            }
        }
    }
    __syncthreads();

    // ---- fallback: fp64 exact rescan for uncertified tokens ----
    const int nq = qn;
    if (nq > 0) {
        fbest[tid] = 1e300;
        fidx[tid]  = 0;
        for (int ch = 0; ch < 16; ++ch) {
            __syncthreads();
            {   // stage 64 codes (fp32) into padded LDS
                int row = tid >> 2, c0 = (tid & 3) * 16;
                const float* srcp = cb + (size_t)(ch * 64 + row) * DIM + c0;
                #pragma unroll
                for (int jj = 0; jj < 16; ++jj) ebuf[row][c0 + jj] = srcp[jj];
            }
            __syncthreads();
            for (int qi = wave; qi < nq; qi += 4) {
                int tl = queue[qi];
                int g  = blockIdx.x * 256 + tl;
                int gb = g >> 13, gt = g & 8191;
                float xl = in[(size_t)gb * DIM * T_LEN + (size_t)lane * T_LEN + gt];  // d = lane
                double dsum = 0.0;
                const int mycode = ch * 64 + lane;
                for (int d = 0; d < 64; ++d) {
                    float xd = __shfl(xl, d, 64);
                    float ed = ebuf[lane][d];
                    double df = (double)xd - (double)ed;
                    dsum = fma(df, df, dsum);
                }
                double s = dsum; int ix = mycode;
                #pragma unroll
                for (int off = 1; off < 64; off <<= 1) {
                    double os = __shfl_xor(s, off, 64);
                    int   oix = __shfl_xor(ix, off, 64);
                    bool take = (os < s) || (os == s && oix < ix);
                    s  = take ? os  : s;
                    ix = take ? oix : ix;
                }
                if (lane == 0) {
                    if (s < fbest[tl] || (s == fbest[tl] && ix < fidx[tl])) {
                        fbest[tl] = s; fidx[tl] = ix;
                    }
                }
            }
        }
        __syncthreads();
        if (tid < nq) { int tl = queue[tid]; idx_s[tl] = fidx[tl]; }
        __syncthreads();
    }

    // ---- epilogue: 1 thread per token, gather exact fp32 row + coalesced stores ----
    const int token = blockIdx.x * 256 + tid;
    const int tb = token >> 13;
    const int tt = token & 8191;
    const int my_idx = idx_s[tid];

    out[(size_t)N_TOK * DIM + token] = (float)my_idx;   // index output

    const float* crow = cb + (size_t)my_idx * DIM;
    float* outv = out + (size_t)tb * DIM * T_LEN + tt;
    #pragma unroll
    for (int d0 = 0; d0 < DIM; d0 += 4) {
        float4 v = *reinterpret_cast<const float4*>(crow + d0);  // L2-hot gather
        outv[(size_t)(d0 + 0) * T_LEN] = v.x;
        outv[(size_t)(d0 + 1) * T_LEN] = v.y;
        outv[(size_t)(d0 + 2) * T_LEN] = v.z;
        outv[(size_t)(d0 + 3) * T_LEN] = v.w;
    }
}

extern "C" void kernel_launch(void* const* d_in, const int* in_sizes, int n_in,
                              void* d_out, int out_size, void* d_ws, size_t ws_size,
                              hipStream_t stream) {
    const float* in = (const float*)d_in[0];   // (16, 64, 8192) fp32
    const float* cb = (const float*)d_in[1];   // (1024, 64) fp32
    float* out = (float*)d_out;

    _Float16* w   = (_Float16*)d_ws;                          // 256 KB tiles
    float* wesq = (float*)((char*)d_ws + 64 * 4096);          // 4 KB
    float* wbh2 = (float*)((char*)d_ws + 64 * 4096 + 4096);   // 4 KB
    float* wbl2 = (float*)((char*)d_ws + 64 * 4096 + 8192);   // 4 KB

    vq_prep<<<dim3(64), dim3(256), 0, stream>>>(cb, w, wesq, wbh2, wbl2);
    vq_main<<<dim3(N_TOK / 256), dim3(256), 0, stream>>>(in, cb, w, wesq, wbh2, wbl2, out);
}

// Round 8
// 127.745 us; speedup vs baseline: 2.3656x; 2.3656x over previous
//
#include <hip/hip_runtime.h>
#include <float.h>

#define K_CODES 1024
#define DIM 64
#define T_LEN 8192
#define N_TOK 131072          // 16 * 8192 tokens
#define LO_SCALE 2048.0f

typedef _Float16 half8 __attribute__((ext_vector_type(8)));  // 4 VGPRs: MFMA A/B frag
typedef float    f32x4 __attribute__((ext_vector_type(4)));  // MFMA C/D frag

#define MFMA16(a, b, c) __builtin_amdgcn_mfma_f32_16x16x32_f16((a), (b), (c), 0, 0, 0)

// ---------------- prep: codebook -> tiled f16 hi/lo + 2048*e_sq ----------------
// Tile ct (16 codes) = 4 KB contiguous: hi[q=0..7][code=0..15][j=0..7], lo(x2048) at +1024.
// wesq stores 2048*||e||^2 (exact power-of-2 scale) for the scaled-score argmin.
__global__ void vq_prep(const float* __restrict__ cb,
                        _Float16* __restrict__ w,
                        float* __restrict__ wesq) {
    __shared__ float part[128];
    const int ct   = blockIdx.x;
    const int r    = threadIdx.x;
    const int halF = r >> 7;
    const int rr   = r & 127;
    const int q    = rr >> 4;
    const int code = rr & 15;

    const float* src = cb + (size_t)(ct * 16 + code) * DIM + q * 8;
    float4 v0 = *reinterpret_cast<const float4*>(src);
    float4 v1 = *reinterpret_cast<const float4*>(src + 4);
    float x[8] = {v0.x, v0.y, v0.z, v0.w, v1.x, v1.y, v1.z, v1.w};

    half8 o;
    float psum = 0.0f;
    #pragma unroll
    for (int j = 0; j < 8; ++j) {
        _Float16 h = (_Float16)x[j];
        o[j] = halF ? (_Float16)((x[j] - (float)h) * LO_SCALE) : h;  // (x-h) exact in fp32
        psum = fmaf(x[j], x[j], psum);
    }
    *reinterpret_cast<half8*>(w + (size_t)ct * 2048 + halF * 1024 + q * 128 + code * 8) = o;

    if (halF == 0) part[rr] = psum;
    __syncthreads();
    if (r < 16) {
        float s = 0.0f;
        #pragma unroll
        for (int q2 = 0; q2 < 8; ++q2) s += part[q2 * 16 + r];
        wesq[ct * 16 + r] = s * LO_SCALE;   // pre-scaled: score' = 2048 * score
    }
}

// ---------------- main: r2 structure + setprio(MFMA) + wave time-stagger ----------------
// Ledger r0-r7: loads (r1), chain ILP (r2), occupancy (r3), prefetch depth (r5/r6),
// work-pruning (r7) -- all fail to move the 61us plateau. Counters: MFMA 20us + VALU 19.5us
// + 21us residual = sum-of-pipes, i.e. NO cross-wave MFMA||VALU overlap. m114 proves the
// pipes CAN overlap when waves desynchronize; ours convoy (identical, barrier-free, launched
// together). This round: (a) s_setprio(1) around each 24-MFMA cluster -- the documented
// fix for exactly the independent-wave regime (attn +4-7%, m191); (b) s_sleep time-stagger
// by block/wave parity to break the convoy; (c) first B-loads hoisted above the A-build.
// Numerics BIT-IDENTICAL to r2: same product set, same visit order -- stagger is time-only.
__global__ __launch_bounds__(256, 2)
void vq_main(const float* __restrict__ in,
             const float* __restrict__ cb,
             const _Float16* __restrict__ w,
             const float* __restrict__ wesq,
             float* __restrict__ out) {
    __shared__ float esq_s[K_CODES];   // 4 KB (scaled x2048)
    __shared__ int   idx_s[256];

    const int tid  = threadIdx.x;
    const int wave = tid >> 6;
    const int lane = tid & 63;
    const int lo4  = lane & 15;   // code residue (C col) / token residue (A m)
    const int quad = lane >> 4;   // k-octet selector; token-row group in C

    for (int k = tid; k < K_CODES; k += 256) esq_s[k] = wesq[k];
    __syncthreads();   // only barrier before the epilogue

    // ---- convoy breaker: stagger co-resident waves by ~256-768 cycles ----
    {
        const int ph = ((blockIdx.x & 1) << 1) | (wave & 1);
        if (ph == 1)      __builtin_amdgcn_s_sleep(4);    // ~256 cyc
        else if (ph == 2) __builtin_amdgcn_s_sleep(8);    // ~512 cyc
        else if (ph == 3) __builtin_amdgcn_s_sleep(12);   // ~768 cyc
    }

    const int strip = blockIdx.x * 256 + wave * 64;   // 64 tokens per wave
    const int b  = strip >> 13;
    const int t0 = strip & 8191;

    // B frags (layout HW-verified r6): tile base + lane*8, frags at +0/+512/+1024/+1536
    const _Float16* wb = w + (size_t)lane * 8;

    half8 Ah0, Ah1, Al0, Al1, Bh0, Bh1, Bl0, Bl1;
    float Ae, Be;
    auto loadB = [&](int ct, half8& h0, half8& h1, half8& l0, half8& l1, float& es) {
        const _Float16* p = wb + (size_t)ct * 2048;
        h0 = *reinterpret_cast<const half8*>(p);          // hi, k 0..31
        h1 = *reinterpret_cast<const half8*>(p + 512);    // hi, k 32..63
        l0 = *reinterpret_cast<const half8*>(p + 1024);   // lo(x2048), k 0..31
        l1 = *reinterpret_cast<const half8*>(p + 1536);   // lo(x2048), k 32..63
        es = esq_s[ct * 16 + lo4];
    };

    // hoisted: first two B tiles in flight while the A fragments are built
    loadB(0, Ah0, Ah1, Al0, Al1, Ae);
    loadB(1, Bh0, Bh1, Bl0, Bl1, Be);

    // ---- A fragments: -2x -> ah (f16), ah_s = ah*2048 (exact), al = (x-ah)*2048 ----
    const float* xin = in + (size_t)b * DIM * T_LEN + t0;
    half8 a_h[4][2], a_hs[4][2], a_l[4][2];
    #pragma unroll
    for (int mt = 0; mt < 4; ++mt) {
        #pragma unroll
        for (int s = 0; s < 2; ++s) {
            half8 hh, hs, ll;
            #pragma unroll
            for (int j = 0; j < 8; ++j) {
                const int d = s * 32 + quad * 8 + j;
                float xv = -2.0f * xin[(size_t)d * T_LEN + mt * 16 + lo4];
                _Float16 h = (_Float16)xv;
                hh[j] = h;
                hs[j] = (_Float16)((float)h * LO_SCALE);            // exact exponent shift
                ll[j] = (_Float16)((xv - (float)h) * LO_SCALE);
            }
            a_h[mt][s] = hh;
            a_hs[mt][s] = hs;
            a_l[mt][s] = ll;
        }
    }

    float best[16];
    int   bidx[16];
    #pragma unroll
    for (int i = 0; i < 16; ++i) { best[i] = FLT_MAX; bidx[i] = 0; }

    // Interleaved issue: 4 independent accumulator chains, pass-outer / mt-inner.
    // Same per-chain MFMA order as r0/r2 -> bit-identical scores.
    auto step = [&](const half8& h0, const half8& h1, const half8& l0,
                    const half8& l1, float es, int ct) {
        const int code = ct * 16 + lo4;
        f32x4 c0 = {es, es, es, es}, c1 = {es, es, es, es};
        f32x4 c2 = {es, es, es, es}, c3 = {es, es, es, es};
        __builtin_amdgcn_s_setprio(1);     // favor this wave while its MFMA burst runs
        c0 = MFMA16(a_hs[0][0], h0, c0);   // pass 1: 2048*ah*bh (k 0..31)
        c1 = MFMA16(a_hs[1][0], h0, c1);
        c2 = MFMA16(a_hs[2][0], h0, c2);
        c3 = MFMA16(a_hs[3][0], h0, c3);
        c0 = MFMA16(a_hs[0][1], h1, c0);   // pass 2: 2048*ah*bh (k 32..63)
        c1 = MFMA16(a_hs[1][1], h1, c1);
        c2 = MFMA16(a_hs[2][1], h1, c2);
        c3 = MFMA16(a_hs[3][1], h1, c3);
        c0 = MFMA16(a_h[0][0], l0, c0);    // pass 3: ah*(2048*bl)
        c1 = MFMA16(a_h[1][0], l0, c1);
        c2 = MFMA16(a_h[2][0], l0, c2);
        c3 = MFMA16(a_h[3][0], l0, c3);
        c0 = MFMA16(a_h[0][1], l1, c0);    // pass 4
        c1 = MFMA16(a_h[1][1], l1, c1);
        c2 = MFMA16(a_h[2][1], l1, c2);
        c3 = MFMA16(a_h[3][1], l1, c3);
        c0 = MFMA16(a_l[0][0], h0, c0);    // pass 5: (2048*al)*bh
        c1 = MFMA16(a_l[1][0], h0, c1);
        c2 = MFMA16(a_l[2][0], h0, c2);
        c3 = MFMA16(a_l[3][0], h0, c3);
        c0 = MFMA16(a_l[0][1], h1, c0);    // pass 6
        c1 = MFMA16(a_l[1][1], h1, c1);
        c2 = MFMA16(a_l[2][1], h1, c2);
        c3 = MFMA16(a_l[3][1], h1, c3);
        __builtin_amdgcn_s_setprio(0);     // back to normal for the argmin VALU burst
        f32x4 cc[4] = {c0, c1, c2, c3};
        #pragma unroll
        for (int mt = 0; mt < 4; ++mt) {
            #pragma unroll
            for (int r = 0; r < 4; ++r) {
                float sc = cc[mt][r];           // scaled score, no fmaf needed
                const int i = mt * 4 + r;
                bool lt = sc < best[i];         // strict <: first occurrence wins
                best[i] = lt ? sc : best[i];
                bidx[i] = lt ? code : bidx[i];
            }
        }
    };

    // ping-pong: tile ct+1's 4 global loads in flight during tile ct's 24 MFMAs
    for (int p = 0; p < 31; ++p) {
        step(Ah0, Ah1, Al0, Al1, Ae, 2 * p);
        loadB(2 * p + 2, Ah0, Ah1, Al0, Al1, Ae);
        step(Bh0, Bh1, Bl0, Bl1, Be, 2 * p + 1);
        loadB(2 * p + 3, Bh0, Bh1, Bl0, Bl1, Be);
    }
    step(Ah0, Ah1, Al0, Al1, Ae, 62);
    step(Bh0, Bh1, Bl0, Bl1, Be, 63);

    // ---- cross-lane merge over the 16 code-residue lanes ----
    #pragma unroll
    for (int i = 0; i < 16; ++i) {
        float s = best[i];
        int  ix = bidx[i];
        #pragma unroll
        for (int off = 1; off < 16; off <<= 1) {
            float s2 = __shfl_xor(s, off, 64);
            int  ix2 = __shfl_xor(ix, off, 64);
            bool take = (s2 < s) || (s2 == s && ix2 < ix);  // tie -> lower index
            s  = take ? s2 : s;
            ix = take ? ix2 : ix;
        }
        if (lo4 == 0) {
            // token_local = mt*16 + quad*4 + r,  mt = i>>2, r = i&3
            idx_s[wave * 64 + (i >> 2) * 16 + quad * 4 + (i & 3)] = ix;
        }
    }
    __syncthreads();

    // ---- epilogue: 1 thread per token, gather exact fp32 row + coalesced stores ----
    const int token = blockIdx.x * 256 + tid;
    const int tb = token >> 13;
    const int tt = token & 8191;
    const int my_idx = idx_s[tid];

    out[(size_t)N_TOK * DIM + token] = (float)my_idx;   // index output

    const float* crow = cb + (size_t)my_idx * DIM;
    float* outv = out + (size_t)tb * DIM * T_LEN + tt;
    #pragma unroll
    for (int d0 = 0; d0 < DIM; d0 += 4) {
        float4 v = *reinterpret_cast<const float4*>(crow + d0);  // L2-hot gather
        outv[(size_t)(d0 + 0) * T_LEN] = v.x;
        outv[(size_t)(d0 + 1) * T_LEN] = v.y;
        outv[(size_t)(d0 + 2) * T_LEN] = v.z;
        outv[(size_t)(d0 + 3) * T_LEN] = v.w;
    }
}

extern "C" void kernel_launch(void* const* d_in, const int* in_sizes, int n_in,
                              void* d_out, int out_size, void* d_ws, size_t ws_size,
                              hipStream_t stream) {
    const float* in = (const float*)d_in[0];   // (16, 64, 8192) fp32
    const float* cb = (const float*)d_in[1];   // (1024, 64) fp32
    float* out = (float*)d_out;

    _Float16* w   = (_Float16*)d_ws;                       // 64 tiles * 4 KB = 256 KB
    float*   wesq = (float*)((char*)d_ws + 64 * 4096);     // 4 KB

    vq_prep<<<dim3(64), dim3(256), 0, stream>>>(cb, w, wesq);
    vq_main<<<dim3(N_TOK / 256), dim3(256), 0, stream>>>(in, cb, w, wesq, out);
}